// Round 1
// baseline (927.589 us; speedup 1.0000x reference)
//
#include <hip/hip_runtime.h>
#include <hip/hip_bf16.h>

// Problem constants (from reference): N=4, S=2048, D_MODEL=1024, HEADS=16, HEAD_DIM=64
// M = N*S = 8192 tokens. QKV width E = 3072.

typedef __hip_bfloat16 bf16;

__device__ __forceinline__ float b2f(unsigned short u) {
    return __uint_as_float(((unsigned)u) << 16);
}
__device__ __forceinline__ unsigned short f2b(float f) {
    __hip_bfloat16 h = __float2bfloat16(f);
    return *reinterpret_cast<unsigned short*>(&h);
}

// ---- 4-wide loads (fp32 or bf16 source), producing fp32 ----
__device__ __forceinline__ void load4(const float* p, float v[4]) {
    float4 x = *reinterpret_cast<const float4*>(p);
    v[0] = x.x; v[1] = x.y; v[2] = x.z; v[3] = x.w;
}
__device__ __forceinline__ void load4(const bf16* p, float v[4]) {
    ushort4 x = *reinterpret_cast<const ushort4*>(p);
    v[0] = b2f(x.x); v[1] = b2f(x.y); v[2] = b2f(x.z); v[3] = b2f(x.w);
}

__device__ __forceinline__ void store1(float* p, float v) { *p = v; }
__device__ __forceinline__ void store1(bf16* p, float v) { *p = __float2bfloat16(v); }

// ---- Tiled GEMM: C[M][N] = A[M][K] * B[N][K]^T + bias[N] ----
// A: fp32 or bf16 row-major (K contiguous). B: fp32 row-major (K contiguous).
// BM=BN=64, BK=32, 256 threads, 4x4 micro-tile per thread.
template <typename AT, typename CT>
__global__ __launch_bounds__(256)
void gemm_nt(const AT* __restrict__ A, const float* __restrict__ B,
             const float* __restrict__ bias, CT* __restrict__ C,
             int M, int N, int K) {
    __shared__ float As[32][68];  // [k][m], padded to keep 16B alignment + spread banks
    __shared__ float Bs[32][68];  // [k][n]

    const int t  = threadIdx.x;
    const int m0 = blockIdx.y * 64;
    const int n0 = blockIdx.x * 64;

    const int kq = t & 7;    // k-quad 0..7 (4 floats each -> 32 k)
    const int rr = t >> 3;   // row 0..31 (two halves -> 64 rows)

    const int tx = t & 15;   // output col group
    const int ty = t >> 4;   // output row group

    float acc[4][4] = {};

    for (int k0 = 0; k0 < K; k0 += 32) {
#pragma unroll
        for (int half = 0; half < 2; ++half) {
            int r = rr + half * 32;
            float av[4], bv[4];
            load4(&A[(size_t)(m0 + r) * K + k0 + kq * 4], av);
            load4(&B[(size_t)(n0 + r) * K + k0 + kq * 4], bv);
#pragma unroll
            for (int j = 0; j < 4; ++j) {
                As[kq * 4 + j][r] = av[j];
                Bs[kq * 4 + j][r] = bv[j];
            }
        }
        __syncthreads();
#pragma unroll
        for (int kk = 0; kk < 32; ++kk) {
            float4 a4 = *reinterpret_cast<const float4*>(&As[kk][ty * 4]);
            float4 b4 = *reinterpret_cast<const float4*>(&Bs[kk][tx * 4]);
            float a[4] = {a4.x, a4.y, a4.z, a4.w};
            float b[4] = {b4.x, b4.y, b4.z, b4.w};
#pragma unroll
            for (int i = 0; i < 4; ++i)
#pragma unroll
                for (int j = 0; j < 4; ++j)
                    acc[i][j] += a[i] * b[j];
        }
        __syncthreads();
    }

#pragma unroll
    for (int i = 0; i < 4; ++i) {
        size_t row = (size_t)(m0 + ty * 4 + i);
#pragma unroll
        for (int j = 0; j < 4; ++j) {
            int col = n0 + tx * 4 + j;
            store1(&C[row * N + col], acc[i][j] + bias[col]);
        }
    }
}

// ---- Per-token attention over heads axis + scrambled T write ----
// For token (n,s): Q[q][d]=qkv[n,s,q*64+d], K[k][d]=qkv[n,s,1024+k*64+d],
// V[l][d]=qkv[n,s,2048+l*64+d].  E[q][k]=sum_d Q[q][d]K[k][d];
// P=softmax(E/8, over k); O[q][d]=sum_l P[q][l]V[l][d].
// T layout (GEMM2 input): T[n, s'=q*128+(s>>4), (s&15)*64+d] = O[q][d].
__global__ __launch_bounds__(256)
void attn_kernel(const bf16* __restrict__ qkv, bf16* __restrict__ T) {
    __shared__ float lds[4][48 * 65];  // per-wave token buffer, row stride 65

    const int wave = threadIdx.x >> 6;
    const int lane = threadIdx.x & 63;
    const int token = blockIdx.x * 4 + wave;
    const int n = token >> 11;      // 2048 tokens per batch
    const int s = token & 2047;

    float* L = lds[wave];
    const bf16* src = qkv + (size_t)token * 3072;

    // stage 3072 bf16 -> fp32 LDS (rows of 64, stride 65)
#pragma unroll
    for (int i = 0; i < 6; ++i) {
        int idx = i * 64 + lane;            // uint4 index (8 bf16 each)
        uint4 v = *reinterpret_cast<const uint4*>(src + (size_t)idx * 8);
        int e0 = idx * 8;
        float* dst = &L[(e0 >> 6) * 65 + (e0 & 63)];
        dst[0] = b2f((unsigned short)(v.x & 0xffff));
        dst[1] = b2f((unsigned short)(v.x >> 16));
        dst[2] = b2f((unsigned short)(v.y & 0xffff));
        dst[3] = b2f((unsigned short)(v.y >> 16));
        dst[4] = b2f((unsigned short)(v.z & 0xffff));
        dst[5] = b2f((unsigned short)(v.z >> 16));
        dst[6] = b2f((unsigned short)(v.w & 0xffff));
        dst[7] = b2f((unsigned short)(v.w >> 16));
    }
    __syncthreads();

    const int q0 = lane & 15;   // head (output row of E)
    const int g  = lane >> 4;   // group 0..3: owns k = g*4..g*4+3, d = g*16..g*16+15

    // E rows (4 per lane), scaled by 1/sqrt(64)
    float e[4] = {0.f, 0.f, 0.f, 0.f};
    const float* Qr = &L[q0 * 65];
    for (int d = 0; d < 64; ++d) {
        float qv = Qr[d];
#pragma unroll
        for (int j = 0; j < 4; ++j)
            e[j] += qv * L[(16 + g * 4 + j) * 65 + d];
    }
#pragma unroll
    for (int j = 0; j < 4; ++j) e[j] *= 0.125f;

    // softmax over k (16 entries spread across 4 lanes sharing q0)
    float m = fmaxf(fmaxf(e[0], e[1]), fmaxf(e[2], e[3]));
    m = fmaxf(m, __shfl_xor(m, 16));
    m = fmaxf(m, __shfl_xor(m, 32));
    float p[4], sum = 0.f;
#pragma unroll
    for (int j = 0; j < 4; ++j) { p[j] = __expf(e[j] - m); sum += p[j]; }
    sum += __shfl_xor(sum, 16);
    sum += __shfl_xor(sum, 32);
    const float inv = 1.0f / sum;

    // gather full P row (16 values) to every lane
    float prow[16];
#pragma unroll
    for (int j = 0; j < 4; ++j) {
        prow[g * 4 + j]         = p[j] * inv;
        prow[((g ^ 1) * 4) + j] = __shfl_xor(p[j], 16) * inv;
        prow[((g ^ 2) * 4) + j] = __shfl_xor(p[j], 32) * inv;
        prow[((g ^ 3) * 4) + j] = __shfl_xor(p[j], 48) * inv;
    }

    // O[q0][d0..d0+15] = P row . V columns ; write scrambled into T
    unsigned short outv[16];
    const int d0 = g * 16;
#pragma unroll
    for (int dd = 0; dd < 16; ++dd) {
        float o = 0.f;
#pragma unroll
        for (int k = 0; k < 16; ++k)
            o += prow[k] * L[(32 + k) * 65 + d0 + dd];
        outv[dd] = f2b(o);
    }
    const int sp = q0 * 128 + (s >> 4);
    size_t off = ((size_t)n * 2048 + sp) * 1024 + (size_t)(s & 15) * 64 + d0;
    uint4* dst = reinterpret_cast<uint4*>(T + off);
    const uint4* sv = reinterpret_cast<const uint4*>(outv);
    dst[0] = sv[0];
    dst[1] = sv[1];
}

extern "C" void kernel_launch(void* const* d_in, const int* in_sizes, int n_in,
                              void* d_out, int out_size, void* d_ws, size_t ws_size,
                              hipStream_t stream) {
    const float* x      = (const float*)d_in[0];   // (4,2048,1024)
    const float* w_qkv  = (const float*)d_in[1];   // (3072,1024)
    const float* b_qkv  = (const float*)d_in[2];   // (3072,)
    const float* w_out  = (const float*)d_in[3];   // (1024,1024)
    const float* b_out  = (const float*)d_in[4];   // (1024,)
    float* out = (float*)d_out;                    // (4,2048,1024) fp32

    const int M = 8192, E = 3072, K = 1024, D = 1024;

    bf16* qkv = (bf16*)d_ws;                       // 8192*3072 bf16 = 50.3 MB
    bf16* T   = qkv + (size_t)M * E;               // 8192*1024 bf16 = 16.8 MB

    dim3 blk(256);
    // 1) QKV projection -> bf16
    gemm_nt<float, bf16><<<dim3(E / 64, M / 64), blk, 0, stream>>>(
        x, w_qkv, b_qkv, qkv, M, E, K);
    // 2) per-token heads-axis attention + scrambled reshape -> bf16 T
    attn_kernel<<<dim3(M / 4), blk, 0, stream>>>(qkv, T);
    // 3) output projection -> fp32
    gemm_nt<bf16, float><<<dim3(D / 64, M / 64), blk, 0, stream>>>(
        T, w_out, b_out, out, M, D, K);
}

// Round 2
// 155.939 us; speedup vs baseline: 5.9484x; 5.9484x over previous
//
#include <hip/hip_runtime.h>
#include <hip/hip_bf16.h>

// N=4, S=2048, D_MODEL=1024, HEADS=16, HEAD_DIM=64. M = 8192 tokens, E = 3072.

typedef __hip_bfloat16 bf16;
using bf16x8 = __attribute__((ext_vector_type(8))) short;
using f32x4  = __attribute__((ext_vector_type(4))) float;

__device__ __forceinline__ float b2f(unsigned short u) {
    return __uint_as_float(((unsigned)u) << 16);
}
__device__ __forceinline__ unsigned short f2b(float f) {
    bf16 h = __float2bfloat16(f);
    return *reinterpret_cast<unsigned short*>(&h);
}
__device__ __forceinline__ void store1(float* p, float v) { *p = v; }
__device__ __forceinline__ void store1(bf16* p, float v) { *p = __float2bfloat16(v); }

// async global->LDS, 16B per lane. LDS dest = wave-uniform base + lane*16.
__device__ __forceinline__ void gload_lds16(const bf16* g, bf16* l) {
    __builtin_amdgcn_global_load_lds(
        (const __attribute__((address_space(1))) void*)g,
        (__attribute__((address_space(3))) void*)l, 16, 0, 0);
}

__device__ __forceinline__ uint4 pack8(float4 a, float4 b) {
    uint4 r;
    r.x = (unsigned)f2b(a.x) | ((unsigned)f2b(a.y) << 16);
    r.y = (unsigned)f2b(a.z) | ((unsigned)f2b(a.w) << 16);
    r.z = (unsigned)f2b(b.x) | ((unsigned)f2b(b.y) << 16);
    r.w = (unsigned)f2b(b.z) | ((unsigned)f2b(b.w) << 16);
    return r;
}

// ---- MFMA GEMM: C[M][N] = A[M][K] * B[N][K]^T + bias[N] ----
// A: bf16 row-major, staged via global_load_lds (lane-linear == row-major [row][32k]).
// B: if BF32, fp32 row-major, reg-staged + converted, XOR-swizzled LDS; else bf16 like A.
// 128x128 tile, BK=32, 256 threads = 4 waves (2x2), 4x4 16x16x32 frags per wave.
template <bool BF32, typename CT>
__global__ __launch_bounds__(256)
void gemm_mfma(const bf16* __restrict__ A, const void* __restrict__ Bv,
               const float* __restrict__ bias, CT* __restrict__ C,
               int M, int N, int K) {
    __shared__ __align__(16) bf16 As[128 * 32];
    __shared__ __align__(16) bf16 Bs[128 * 32];

    const int t    = threadIdx.x;
    const int lane = t & 63;
    const int wid  = t >> 6;
    const int wr   = wid >> 1;   // wave row (0..1)
    const int wc   = wid & 1;    // wave col (0..1)
    const int m0   = blockIdx.y * 128;
    const int n0   = blockIdx.x * 128;

    f32x4 acc[4][4] = {};

    // A staging: wave wid stages rows wid*32..+31; lane l -> row wid*32+(l>>2), k (l&3)*8
    const bf16* gA = A + (size_t)(m0 + wid * 32 + (lane >> 2)) * K + (lane & 3) * 8;
    bf16* lA = &As[wid * 1024];
    const bf16* gB16 = nullptr;
    bf16* lB = &Bs[wid * 1024];
    if constexpr (!BF32)
        gB16 = (const bf16*)Bv + (size_t)(n0 + wid * 32 + (lane >> 2)) * K + (lane & 3) * 8;

    for (int k0 = 0; k0 < K; k0 += 32) {
        gload_lds16(gA, lA);
        gload_lds16(gA + (size_t)16 * K, lA + 512);
        gA += 32;
        if constexpr (BF32) {
            const float* B = (const float*)Bv;
            const int row = wid * 32 + (lane >> 1);      // tile-local B row
            const float* gB = B + (size_t)(n0 + row) * K + k0 + (lane & 1) * 16;
            float4 f0 = ((const float4*)gB)[0];
            float4 f1 = ((const float4*)gB)[1];
            float4 f2 = ((const float4*)gB)[2];
            float4 f3 = ((const float4*)gB)[3];
            uint4 c0 = pack8(f0, f1), c1 = pack8(f2, f3);
            const int byte0 = row * 64 + (lane & 1) * 32;
            const int swz = (row & 7) << 4;
            *(uint4*)((char*)Bs + (byte0 ^ swz))        = c0;
            *(uint4*)((char*)Bs + ((byte0 + 16) ^ swz)) = c1;
        } else {
            gload_lds16(gB16, lB);
            gload_lds16(gB16 + (size_t)16 * K, lB + 512);
            gB16 += 32;
        }
        __syncthreads();

        bf16x8 af[4], bfr[4];
        const int kb = (lane >> 4) * 16;  // k byte offset for this lane
#pragma unroll
        for (int i = 0; i < 4; ++i) {
            const int arow = wr * 64 + i * 16 + (lane & 15);
            af[i] = *(const bf16x8*)((const char*)As + arow * 64 + kb);
            const int brow = wc * 64 + i * 16 + (lane & 15);
            int bbyte = brow * 64 + kb;
            if (BF32) bbyte ^= (brow & 7) << 4;
            bfr[i] = *(const bf16x8*)((const char*)Bs + bbyte);
        }
#pragma unroll
        for (int i = 0; i < 4; ++i)
#pragma unroll
            for (int j = 0; j < 4; ++j)
                acc[i][j] = __builtin_amdgcn_mfma_f32_16x16x32_bf16(
                    af[i], bfr[j], acc[i][j], 0, 0, 0);
        __syncthreads();
    }

#pragma unroll
    for (int i = 0; i < 4; ++i) {
        const int row = m0 + wr * 64 + i * 16 + (lane >> 4) * 4;
#pragma unroll
        for (int j = 0; j < 4; ++j) {
            const int col = n0 + wc * 64 + j * 16 + (lane & 15);
            const float bval = bias[col];
#pragma unroll
            for (int r = 0; r < 4; ++r)
                store1(&C[(size_t)(row + r) * N + col], acc[i][j][r] + bval);
        }
    }
}

// ---- fp32 -> bf16 conversion, 4 elems/thread ----
__global__ __launch_bounds__(256)
void cvt_f32_bf16(const float* __restrict__ in, bf16* __restrict__ out, int n4) {
    int i = blockIdx.x * 256 + threadIdx.x;
    if (i >= n4) return;
    float4 v = ((const float4*)in)[i];
    ushort4 o = {f2b(v.x), f2b(v.y), f2b(v.z), f2b(v.w)};
    ((ushort4*)out)[i] = o;
}

// ---- Per-token attention over heads axis + scrambled T write ----
__global__ __launch_bounds__(256)
void attn_kernel(const bf16* __restrict__ qkv, bf16* __restrict__ T) {
    __shared__ float lds[4][48 * 65];

    const int wave = threadIdx.x >> 6;
    const int lane = threadIdx.x & 63;
    const int token = blockIdx.x * 4 + wave;
    const int n = token >> 11;
    const int s = token & 2047;

    float* L = lds[wave];
    const bf16* src = qkv + (size_t)token * 3072;

#pragma unroll
    for (int i = 0; i < 6; ++i) {
        int idx = i * 64 + lane;
        uint4 v = *reinterpret_cast<const uint4*>(src + (size_t)idx * 8);
        int e0 = idx * 8;
        float* dst = &L[(e0 >> 6) * 65 + (e0 & 63)];
        dst[0] = b2f((unsigned short)(v.x & 0xffff));
        dst[1] = b2f((unsigned short)(v.x >> 16));
        dst[2] = b2f((unsigned short)(v.y & 0xffff));
        dst[3] = b2f((unsigned short)(v.y >> 16));
        dst[4] = b2f((unsigned short)(v.z & 0xffff));
        dst[5] = b2f((unsigned short)(v.z >> 16));
        dst[6] = b2f((unsigned short)(v.w & 0xffff));
        dst[7] = b2f((unsigned short)(v.w >> 16));
    }
    __syncthreads();

    const int q0 = lane & 15;
    const int g  = lane >> 4;

    float e[4] = {0.f, 0.f, 0.f, 0.f};
    const float* Qr = &L[q0 * 65];
    for (int d = 0; d < 64; ++d) {
        float qv = Qr[d];
#pragma unroll
        for (int j = 0; j < 4; ++j)
            e[j] += qv * L[(16 + g * 4 + j) * 65 + d];
    }
#pragma unroll
    for (int j = 0; j < 4; ++j) e[j] *= 0.125f;

    float m = fmaxf(fmaxf(e[0], e[1]), fmaxf(e[2], e[3]));
    m = fmaxf(m, __shfl_xor(m, 16));
    m = fmaxf(m, __shfl_xor(m, 32));
    float p[4], sum = 0.f;
#pragma unroll
    for (int j = 0; j < 4; ++j) { p[j] = __expf(e[j] - m); sum += p[j]; }
    sum += __shfl_xor(sum, 16);
    sum += __shfl_xor(sum, 32);
    const float inv = 1.0f / sum;

    float prow[16];
#pragma unroll
    for (int j = 0; j < 4; ++j) {
        prow[g * 4 + j]         = p[j] * inv;
        prow[((g ^ 1) * 4) + j] = __shfl_xor(p[j], 16) * inv;
        prow[((g ^ 2) * 4) + j] = __shfl_xor(p[j], 32) * inv;
        prow[((g ^ 3) * 4) + j] = __shfl_xor(p[j], 48) * inv;
    }

    unsigned short outv[16];
    const int d0 = g * 16;
#pragma unroll
    for (int dd = 0; dd < 16; ++dd) {
        float o = 0.f;
#pragma unroll
        for (int k = 0; k < 16; ++k)
            o += prow[k] * L[(32 + k) * 65 + d0 + dd];
        outv[dd] = f2b(o);
    }
    const int sp = q0 * 128 + (s >> 4);
    size_t off = ((size_t)n * 2048 + sp) * 1024 + (size_t)(s & 15) * 64 + d0;
    uint4* dst = reinterpret_cast<uint4*>(T + off);
    const uint4* sv = reinterpret_cast<const uint4*>(outv);
    dst[0] = sv[0];
    dst[1] = sv[1];
}

extern "C" void kernel_launch(void* const* d_in, const int* in_sizes, int n_in,
                              void* d_out, int out_size, void* d_ws, size_t ws_size,
                              hipStream_t stream) {
    const float* x     = (const float*)d_in[0];   // (4,2048,1024)
    const float* w_qkv = (const float*)d_in[1];   // (3072,1024)
    const float* b_qkv = (const float*)d_in[2];   // (3072,)
    const float* w_out = (const float*)d_in[3];   // (1024,1024)
    const float* b_out = (const float*)d_in[4];   // (1024,)
    float* out = (float*)d_out;                   // (4,2048,1024) fp32

    const int M = 8192, E = 3072, K = 1024, D = 1024;

    // ws layout (fits in proven 64 MiB):
    //   [0, 50.33M):       qkv bf16 (GEMM1 out) -> later W2 (after attn)
    //   [50.33M, 67.11M):  x_bf16 (GEMM1 in) -> later T (attn out)
    bf16* qkv = (bf16*)d_ws;
    bf16* X16 = qkv + (size_t)M * E;
    bf16* T   = X16;                 // alias: X16 dead when attn writes T
    bf16* W2  = qkv;                 // alias: qkv dead when W2 written

    dim3 blk(256);

    // 1) x fp32 -> bf16
    cvt_f32_bf16<<<dim3((M * K / 4 + 255) / 256), blk, 0, stream>>>(x, X16, M * K / 4);
    // 2) QKV projection (A=x bf16 async-LDS, B=w_qkv fp32 reg-convert) -> bf16 qkv
    gemm_mfma<true, bf16><<<dim3(E / 128, M / 128), blk, 0, stream>>>(
        X16, (const void*)w_qkv, b_qkv, qkv, M, E, K);
    // 3) per-token heads-axis attention + scrambled reshape -> bf16 T (over X16)
    attn_kernel<<<dim3(M / 4), blk, 0, stream>>>(qkv, T);
    // 4) w_out fp32 -> bf16 (into dead qkv region)
    cvt_f32_bf16<<<dim3((D * K / 4 + 255) / 256), blk, 0, stream>>>(w_out, W2, D * K / 4);
    // 5) output projection -> fp32
    gemm_mfma<false, float><<<dim3(D / 128, M / 128), blk, 0, stream>>>(
        T, (const void*)W2, b_out, out, M, D, K);
}

// Round 3
// 138.105 us; speedup vs baseline: 6.7166x; 1.1291x over previous
//
#include <hip/hip_runtime.h>
#include <hip/hip_bf16.h>

// N=4, S=2048, D_MODEL=1024, HEADS=16, HEAD_DIM=64. M = 8192 tokens, E = 3072.

typedef __hip_bfloat16 bf16;
using bf16x8 = __attribute__((ext_vector_type(8))) short;
using f32x4  = __attribute__((ext_vector_type(4))) float;

__device__ __forceinline__ float b2f(unsigned short u) {
    return __uint_as_float(((unsigned)u) << 16);
}
__device__ __forceinline__ unsigned short f2b(float f) {
    bf16 h = __float2bfloat16(f);
    return *reinterpret_cast<unsigned short*>(&h);
}
__device__ __forceinline__ void store1(float* p, float v) { *p = v; }
__device__ __forceinline__ void store1(bf16* p, float v) { *p = __float2bfloat16(v); }

// async global->LDS, 16B per lane. LDS dest = wave-uniform base + lane*16.
__device__ __forceinline__ void gload_lds16(const bf16* g, bf16* l) {
    __builtin_amdgcn_global_load_lds(
        (const __attribute__((address_space(1))) void*)g,
        (__attribute__((address_space(3))) void*)l, 16, 0, 0);
}

// ---- MFMA GEMM: C[M][N] = A[M][K] * B[N][K]^T + bias[N] ----
// Both A,B bf16 row-major (K contiguous), staged via global_load_lds.
// 128x128 tile, BK=32, 256 threads = 4 waves (2x2), 4x4 16x16x32 frags/wave.
// 2-phase: prefetch tile t+1 into buf^1 BEFORE computing tile t (T3 min recipe).
template <typename CT>
__global__ __launch_bounds__(256)
void gemm_mfma(const bf16* __restrict__ A, const bf16* __restrict__ B,
               const float* __restrict__ bias, CT* __restrict__ C,
               int M, int N, int K) {
    __shared__ __align__(16) bf16 As[2][128 * 32];
    __shared__ __align__(16) bf16 Bs[2][128 * 32];

    const int t    = threadIdx.x;
    const int lane = t & 63;
    const int wid  = t >> 6;
    const int wr   = wid >> 1;   // wave row (0..1)
    const int wc   = wid & 1;    // wave col (0..1)
    const int m0   = blockIdx.y * 128;
    const int n0   = blockIdx.x * 128;

    f32x4 acc[4][4] = {};

    // wave wid stages rows wid*32..+31; lane l -> row wid*32+(l>>2), k (l&3)*8
    const bf16* gA = A + (size_t)(m0 + wid * 32 + (lane >> 2)) * K + (lane & 3) * 8;
    const bf16* gB = B + (size_t)(n0 + wid * 32 + (lane >> 2)) * K + (lane & 3) * 8;
    const int lofs = wid * 1024;

    const int nt = K / 32;

    // prologue: stage tile 0 into buf 0
    gload_lds16(gA, &As[0][lofs]);
    gload_lds16(gA + (size_t)16 * K, &As[0][lofs + 512]);
    gload_lds16(gB, &Bs[0][lofs]);
    gload_lds16(gB + (size_t)16 * K, &Bs[0][lofs + 512]);
    gA += 32; gB += 32;
    __syncthreads();

    int cur = 0;
    for (int tt = 0; tt < nt; ++tt) {
        // prefetch next tile into buf cur^1 (loads fly during compute below)
        if (tt + 1 < nt) {
            const int nb = cur ^ 1;
            gload_lds16(gA, &As[nb][lofs]);
            gload_lds16(gA + (size_t)16 * K, &As[nb][lofs + 512]);
            gload_lds16(gB, &Bs[nb][lofs]);
            gload_lds16(gB + (size_t)16 * K, &Bs[nb][lofs + 512]);
            gA += 32; gB += 32;
        }

        bf16x8 af[4], bfr[4];
        const int kb = (lane >> 4) * 16;  // k byte offset for this lane
#pragma unroll
        for (int i = 0; i < 4; ++i) {
            const int arow = wr * 64 + i * 16 + (lane & 15);
            af[i] = *(const bf16x8*)((const char*)As[cur] + arow * 64 + kb);
            const int brow = wc * 64 + i * 16 + (lane & 15);
            bfr[i] = *(const bf16x8*)((const char*)Bs[cur] + brow * 64 + kb);
        }
#pragma unroll
        for (int i = 0; i < 4; ++i)
#pragma unroll
            for (int j = 0; j < 4; ++j)
                acc[i][j] = __builtin_amdgcn_mfma_f32_16x16x32_bf16(
                    af[i], bfr[j], acc[i][j], 0, 0, 0);
        __syncthreads();   // drains prefetch vmcnt + all waves done reading buf cur
        cur ^= 1;
    }

#pragma unroll
    for (int i = 0; i < 4; ++i) {
        const int row = m0 + wr * 64 + i * 16 + (lane >> 4) * 4;
#pragma unroll
        for (int j = 0; j < 4; ++j) {
            const int col = n0 + wc * 64 + j * 16 + (lane & 15);
            const float bval = bias[col];
#pragma unroll
            for (int r = 0; r < 4; ++r)
                store1(&C[(size_t)(row + r) * N + col], acc[i][j][r] + bval);
        }
    }
}

// ---- fp32 -> bf16 conversion, 4 elems/thread ----
__global__ __launch_bounds__(256)
void cvt_f32_bf16(const float* __restrict__ in, bf16* __restrict__ out, int n4) {
    int i = blockIdx.x * 256 + threadIdx.x;
    if (i >= n4) return;
    float4 v = ((const float4*)in)[i];
    ushort4 o = {f2b(v.x), f2b(v.y), f2b(v.z), f2b(v.w)};
    ((ushort4*)out)[i] = o;
}

// ---- Per-token attention over heads axis + scrambled T write ----
__global__ __launch_bounds__(256)
void attn_kernel(const bf16* __restrict__ qkv, bf16* __restrict__ T) {
    __shared__ float lds[4][48 * 65];

    const int wave = threadIdx.x >> 6;
    const int lane = threadIdx.x & 63;
    const int token = blockIdx.x * 4 + wave;
    const int n = token >> 11;
    const int s = token & 2047;

    float* L = lds[wave];
    const bf16* src = qkv + (size_t)token * 3072;

#pragma unroll
    for (int i = 0; i < 6; ++i) {
        int idx = i * 64 + lane;
        uint4 v = *reinterpret_cast<const uint4*>(src + (size_t)idx * 8);
        int e0 = idx * 8;
        float* dst = &L[(e0 >> 6) * 65 + (e0 & 63)];
        dst[0] = b2f((unsigned short)(v.x & 0xffff));
        dst[1] = b2f((unsigned short)(v.x >> 16));
        dst[2] = b2f((unsigned short)(v.y & 0xffff));
        dst[3] = b2f((unsigned short)(v.y >> 16));
        dst[4] = b2f((unsigned short)(v.z & 0xffff));
        dst[5] = b2f((unsigned short)(v.z >> 16));
        dst[6] = b2f((unsigned short)(v.w & 0xffff));
        dst[7] = b2f((unsigned short)(v.w >> 16));
    }
    __syncthreads();

    const int q0 = lane & 15;
    const int g  = lane >> 4;

    float e[4] = {0.f, 0.f, 0.f, 0.f};
    const float* Qr = &L[q0 * 65];
    for (int d = 0; d < 64; ++d) {
        float qv = Qr[d];
#pragma unroll
        for (int j = 0; j < 4; ++j)
            e[j] += qv * L[(16 + g * 4 + j) * 65 + d];
    }
#pragma unroll
    for (int j = 0; j < 4; ++j) e[j] *= 0.125f;

    float m = fmaxf(fmaxf(e[0], e[1]), fmaxf(e[2], e[3]));
    m = fmaxf(m, __shfl_xor(m, 16));
    m = fmaxf(m, __shfl_xor(m, 32));
    float p[4], sum = 0.f;
#pragma unroll
    for (int j = 0; j < 4; ++j) { p[j] = __expf(e[j] - m); sum += p[j]; }
    sum += __shfl_xor(sum, 16);
    sum += __shfl_xor(sum, 32);
    const float inv = 1.0f / sum;

    float prow[16];
#pragma unroll
    for (int j = 0; j < 4; ++j) {
        prow[g * 4 + j]         = p[j] * inv;
        prow[((g ^ 1) * 4) + j] = __shfl_xor(p[j], 16) * inv;
        prow[((g ^ 2) * 4) + j] = __shfl_xor(p[j], 32) * inv;
        prow[((g ^ 3) * 4) + j] = __shfl_xor(p[j], 48) * inv;
    }

    unsigned short outv[16];
    const int d0 = g * 16;
#pragma unroll
    for (int dd = 0; dd < 16; ++dd) {
        float o = 0.f;
#pragma unroll
        for (int k = 0; k < 16; ++k)
            o += prow[k] * L[(32 + k) * 65 + d0 + dd];
        outv[dd] = f2b(o);
    }
    const int sp = q0 * 128 + (s >> 4);
    size_t off = ((size_t)n * 2048 + sp) * 1024 + (size_t)(s & 15) * 64 + d0;
    uint4* dst = reinterpret_cast<uint4*>(T + off);
    const uint4* sv = reinterpret_cast<const uint4*>(outv);
    dst[0] = sv[0];
    dst[1] = sv[1];
}

extern "C" void kernel_launch(void* const* d_in, const int* in_sizes, int n_in,
                              void* d_out, int out_size, void* d_ws, size_t ws_size,
                              hipStream_t stream) {
    const float* x     = (const float*)d_in[0];   // (4,2048,1024)
    const float* w_qkv = (const float*)d_in[1];   // (3072,1024)
    const float* b_qkv = (const float*)d_in[2];   // (3072,)
    const float* w_out = (const float*)d_in[3];   // (1024,1024)
    const float* b_out = (const float*)d_in[4];   // (1024,)
    float* out = (float*)d_out;                   // (4,2048,1024) fp32

    const int M = 8192, E = 3072, K = 1024, D = 1024;

    // ws layout: [0, 50.33M) qkv bf16 -> later W2b; [50.33M, 67.11M) T bf16.
    // d_out (33.5MB fp32) doubles as scratch until GEMM2 rewrites it:
    //   [0, 6.29M) W1b (w_qkv bf16), [6.29M, 23.1M) X16 (x bf16).
    bf16* qkv = (bf16*)d_ws;
    bf16* T   = qkv + (size_t)M * E;
    bf16* W2b = qkv;                                  // alias: qkv dead after attn
    bf16* W1b = (bf16*)d_out;                         // scratch in d_out
    bf16* X16 = W1b + (size_t)E * K;                  // scratch in d_out

    dim3 blk(256);

    // 1) x fp32 -> bf16 (into d_out scratch)
    cvt_f32_bf16<<<dim3(M * K / 4 / 256), blk, 0, stream>>>(x, X16, M * K / 4);
    // 2) w_qkv fp32 -> bf16 (into d_out scratch)
    cvt_f32_bf16<<<dim3(E * K / 4 / 256), blk, 0, stream>>>(w_qkv, W1b, E * K / 4);
    // 3) QKV projection (pure bf16, async-LDS both sides) -> bf16 qkv
    gemm_mfma<bf16><<<dim3(E / 128, M / 128), blk, 0, stream>>>(
        X16, W1b, b_qkv, qkv, M, E, K);
    // 4) per-token heads-axis attention + scrambled reshape -> bf16 T
    attn_kernel<<<dim3(M / 4), blk, 0, stream>>>(qkv, T);
    // 5) w_out fp32 -> bf16 (into dead qkv region)
    cvt_f32_bf16<<<dim3(D * K / 4 / 256), blk, 0, stream>>>(w_out, W2b, D * K / 4);
    // 6) output projection -> fp32 d_out (overwrites scratch)
    gemm_mfma<float><<<dim3(D / 128, M / 128), blk, 0, stream>>>(
        T, W2b, b_out, out, M, D, K);
}